// Round 16
// baseline (288.527 us; speedup 1.0000x reference)
//
#include <hip/hip_runtime.h>

#define N_ITER 100

typedef float f32x4 __attribute__((ext_vector_type(4)));
typedef unsigned u32x4 __attribute__((ext_vector_type(4)));

// RNE-pack two f32 into a dword of two bf16 (proven R7-R15: absmax 3.9e-3).
__device__ __forceinline__ unsigned bf16pack(float a, float b) {
  unsigned ua = __float_as_uint(a), ub = __float_as_uint(b);
  ua = (ua + 0x7FFFu + ((ua >> 16) & 1u)) >> 16;
  ub = (ub + 0x7FFFu + ((ub >> 16) & 1u)) >> 16;
  return ua | (ub << 16);
}
__device__ __forceinline__ float bflo(unsigned u) { return __uint_as_float(u << 16); }
__device__ __forceinline__ float bfhi(unsigned u) { return __uint_as_float(u & 0xFFFF0000u); }

// Force a value's virtual register into AGPR class AT DEFINITION (proven R13:
// kills the accvgpr copy tax without the R11/R12 asm-boundary hazards).
__device__ __forceinline__ void pin_agpr(u32x4& x) {
  asm("" : "=a"(x) : "0"(x));
}

// MFMA with A + accumulator pinned to AGPRs, B in VGPRs (R13-proven hazard
// handling: s_nop 2 entry guard, inline-0 SrcC chain start, 24-cyc data-tied
// exit fence before any VALU reads the MFMA destination).
__device__ __forceinline__ void mfma_first(f32x4& acc, const u32x4& a, const u32x4& b) {
  asm("s_nop 2\n\tv_mfma_f32_16x16x32_bf16 %0, %1, %2, 0"
      : "=&a"(acc) : "a"(a), "v"(b));
}
__device__ __forceinline__ void mfma_aa(f32x4& acc, const u32x4& a, const u32x4& b) {
  asm("s_nop 2\n\tv_mfma_f32_16x16x32_bf16 %0, %1, %2, %0"
      : "+a"(acc) : "a"(a), "v"(b));
}
__device__ __forceinline__ void mfma_fence4(f32x4& a0, f32x4& a1, f32x4& a2, f32x4& a3) {
  asm volatile("s_nop 7\n\ts_nop 7\n\ts_nop 7"
               : "+a"(a0), "+a"(a1), "+a"(a2), "+a"(a3));
}

// One block (256 threads = 4 waves) per matrix. Wave w owns rows
// [64w,64w+64) (4 row slabs) and cols [64w,64w+64) (4 col slabs of V0^T),
// fragments pinned in AGPRs (256 AGPR + ~100 VGPR < 512 unified budget at
// 1 wave/SIMD). Rationale: total MFMA work is fixed (256 instr/CU/iter =
// 1024 cyc/SIMD), but B-operand LDS reads scale with wave count -- W=4 puts
// LDS (64 reads ~ 768 cyc) UNDER the MFMA floor, unlike W=8 (1536, R13's
// measured bottleneck). R9's W=4 failure was the un-pinned copy-tax thrash.
// Scales broadcast through the MFMA B operand (all 16 n-cols identical).
// Layouts (m89-verified): A elem j <-> A[m=lane&15][k=8q+j]; D reg r <-> row
// 4q+r, col=lane&15.
__global__ __launch_bounds__(256)
__attribute__((amdgpu_waves_per_eu(1, 1)))
void sinkhorn_mfma4p(const float* __restrict__ alpha, float* __restrict__ out) {
  __shared__ alignas(16) unsigned short Cb16[256];
  __shared__ alignas(16) unsigned short Rb16[256];
  __shared__ alignas(16) float Cb32[256];
  __shared__ alignas(16) float Rb32[256];

  const int tid  = threadIdx.x;
  const int lane = tid & 63;
  const int w    = tid >> 6;   // wave 0..3
  const int m    = lane & 15;
  const int q    = lane >> 4;

  const size_t mbase = (size_t)blockIdx.x * (256 * 256);
  const float* A = alpha + mbase;
  float*       O = out + mbase;

  // arow[s][c] elem j <-> V0[64w+16s+m][32c+8q+j]
  // acol[s][c] elem j <-> V0[32c+8q+j][64w+16s+m]
  u32x4 arow[4][8];
  u32x4 acol[4][8];

#pragma unroll
  for (int s = 0; s < 4; ++s) {
    const float* rowp = A + (size_t)(64 * w + 16 * s + m) * 256 + 8 * q;
#pragma unroll
    for (int c = 0; c < 8; ++c) {
      float4 x0 = *(const float4*)(rowp + 32 * c);
      float4 x1 = *(const float4*)(rowp + 32 * c + 4);
      arow[s][c] = (u32x4){bf16pack(__expf(x0.x * 10.0f), __expf(x0.y * 10.0f)),
                           bf16pack(__expf(x0.z * 10.0f), __expf(x0.w * 10.0f)),
                           bf16pack(__expf(x1.x * 10.0f), __expf(x1.y * 10.0f)),
                           bf16pack(__expf(x1.z * 10.0f), __expf(x1.w * 10.0f))};
    }
    const float* colp = A + (size_t)(8 * q) * 256 + 64 * w + 16 * s + m;
#pragma unroll
    for (int c = 0; c < 8; ++c) {
      const float* p = colp + (size_t)(32 * c) * 256;
      acol[s][c] =
          (u32x4){bf16pack(__expf(p[0] * 10.0f), __expf(p[256] * 10.0f)),
                  bf16pack(__expf(p[512] * 10.0f), __expf(p[768] * 10.0f)),
                  bf16pack(__expf(p[1024] * 10.0f), __expf(p[1280] * 10.0f)),
                  bf16pack(__expf(p[1536] * 10.0f), __expf(p[1792] * 10.0f))};
    }
  }
  // Pin all persistent fragments into AGPRs (one-time, far from MFMAs).
#pragma unroll
  for (int s = 0; s < 4; ++s)
#pragma unroll
    for (int c = 0; c < 8; ++c) {
      pin_agpr(arow[s][c]);
      pin_agpr(acol[s][c]);
    }

  Cb16[tid] = 0x3F80;  // C = 1 (blockDim == 256)
  __syncthreads();

  for (int it = 0; it < N_ITER; ++it) {
    const bool last = (it == N_ITER - 1);

    // ---------- phase 1: s = V0_rowslabs · C ; R = 1/s ----------
    {
      u32x4 B[8];
#pragma unroll
      for (int c = 0; c < 8; ++c) B[c] = *(const u32x4*)&Cb16[32 * c + 8 * q];
      f32x4 acc[4];
#pragma unroll
      for (int s = 0; s < 4; ++s) mfma_first(acc[s], arow[s][0], B[0]);
#pragma unroll
      for (int c = 1; c < 8; ++c)
#pragma unroll
        for (int s = 0; s < 4; ++s) mfma_aa(acc[s], arow[s][c], B[c]);
      mfma_fence4(acc[0], acc[1], acc[2], acc[3]);
      if (m == 0) {  // rows 64w+16s+4q..+3
#pragma unroll
        for (int s = 0; s < 4; ++s) {
          float r0 = __builtin_amdgcn_rcpf(acc[s][0]);
          float r1 = __builtin_amdgcn_rcpf(acc[s][1]);
          float r2 = __builtin_amdgcn_rcpf(acc[s][2]);
          float r3 = __builtin_amdgcn_rcpf(acc[s][3]);
          *(uint2*)&Rb16[64 * w + 16 * s + 4 * q] =
              make_uint2(bf16pack(r0, r1), bf16pack(r2, r3));
          if (last)
            *(float4*)&Rb32[64 * w + 16 * s + 4 * q] = make_float4(r0, r1, r2, r3);
        }
      }
    }
    __syncthreads();

    // ---------- phase 2: t = V0^T_colslabs · R ; C = 1/t ----------
    {
      u32x4 B[8];
#pragma unroll
      for (int c = 0; c < 8; ++c) B[c] = *(const u32x4*)&Rb16[32 * c + 8 * q];
      f32x4 acc[4];
#pragma unroll
      for (int s = 0; s < 4; ++s) mfma_first(acc[s], acol[s][0], B[0]);
#pragma unroll
      for (int c = 1; c < 8; ++c)
#pragma unroll
        for (int s = 0; s < 4; ++s) mfma_aa(acc[s], acol[s][c], B[c]);
      mfma_fence4(acc[0], acc[1], acc[2], acc[3]);
      if (m == 0) {  // cols 64w+16s+4q..+3
#pragma unroll
        for (int s = 0; s < 4; ++s) {
          float c0 = __builtin_amdgcn_rcpf(acc[s][0]);
          float c1 = __builtin_amdgcn_rcpf(acc[s][1]);
          float c2 = __builtin_amdgcn_rcpf(acc[s][2]);
          float c3 = __builtin_amdgcn_rcpf(acc[s][3]);
          *(uint2*)&Cb16[64 * w + 16 * s + 4 * q] =
              make_uint2(bf16pack(c0, c1), bf16pack(c2, c3));
          if (last)
            *(float4*)&Cb32[64 * w + 16 * s + 4 * q] = make_float4(c0, c1, c2, c3);
        }
      }
    }
    __syncthreads();
  }

  // ---------- epilogue: out = diag(R32) · V0_bf16 · diag(C32) ----------
#pragma unroll
  for (int s = 0; s < 4; ++s) {
    const float Rm = Rb32[64 * w + 16 * s + m];
    float* dst = O + (size_t)(64 * w + 16 * s + m) * 256 + 8 * q;
#pragma unroll
    for (int c = 0; c < 8; ++c) {
      float4 c0 = *(const float4*)&Cb32[32 * c + 8 * q];
      float4 c1 = *(const float4*)&Cb32[32 * c + 8 * q + 4];
      u32x4 pk = arow[s][c];
      float4 o0, o1;
      o0.x = bflo(pk.x) * Rm * c0.x;
      o0.y = bfhi(pk.x) * Rm * c0.y;
      o0.z = bflo(pk.y) * Rm * c0.z;
      o0.w = bfhi(pk.y) * Rm * c0.w;
      o1.x = bflo(pk.z) * Rm * c1.x;
      o1.y = bfhi(pk.z) * Rm * c1.y;
      o1.z = bflo(pk.w) * Rm * c1.z;
      o1.w = bfhi(pk.w) * Rm * c1.w;
      *(float4*)(dst + 32 * c) = o0;
      *(float4*)(dst + 32 * c + 4) = o1;
    }
  }
}

extern "C" void kernel_launch(void* const* d_in, const int* in_sizes, int n_in,
                              void* d_out, int out_size, void* d_ws, size_t ws_size,
                              hipStream_t stream) {
  const float* alpha = (const float*)d_in[0];
  float* out = (float*)d_out;
  sinkhorn_mfma4p<<<dim3(16), dim3(256), 0, stream>>>(alpha, out);
}

// Round 17
// 169.183 us; speedup vs baseline: 1.7054x; 1.7054x over previous
//
#include <hip/hip_runtime.h>

#define N_ITER 100

typedef float f32x4 __attribute__((ext_vector_type(4)));
typedef unsigned u32x4 __attribute__((ext_vector_type(4)));

// RNE-pack two f32 into a dword of two bf16 (proven R7-R16: absmax 3.9e-3).
__device__ __forceinline__ unsigned bf16pack(float a, float b) {
  unsigned ua = __float_as_uint(a), ub = __float_as_uint(b);
  ua = (ua + 0x7FFFu + ((ua >> 16) & 1u)) >> 16;
  ub = (ub + 0x7FFFu + ((ub >> 16) & 1u)) >> 16;
  return ua | (ub << 16);
}
__device__ __forceinline__ float bflo(unsigned u) { return __uint_as_float(u << 16); }
__device__ __forceinline__ float bfhi(unsigned u) { return __uint_as_float(u & 0xFFFF0000u); }

// Force a value's virtual register into AGPR class AT DEFINITION (proven R13:
// kills the accvgpr copy tax without the R11/R12 asm-boundary hazards).
__device__ __forceinline__ void pin_agpr(u32x4& x) {
  asm("" : "=a"(x) : "0"(x));
}

// MFMA with A + accumulator pinned to AGPRs, B in VGPRs.
// Hazard audit (R17): interior MFMAs read only B (ds_read-written, waitcnt-
// protected -- not a VALU write), A (AGPR, pinned far away) and acc (MFMA->
// MFMA same-pipe chain, HW-interlocked). So no entry s_nop needed inside the
// chain; keep one s_nop 2 at chain start as insurance against compiler-
// scheduled VALU at block entry, and the proven 24-cyc data-tied exit fence
// before any VALU (v_accvgpr_read) touches the MFMA destination.
__device__ __forceinline__ void mfma_first(f32x4& acc, const u32x4& a, const u32x4& b) {
  asm("s_nop 2\n\tv_mfma_f32_16x16x32_bf16 %0, %1, %2, 0"
      : "=&a"(acc) : "a"(a), "v"(b));
}
__device__ __forceinline__ void mfma_aa(f32x4& acc, const u32x4& a, const u32x4& b) {
  asm("v_mfma_f32_16x16x32_bf16 %0, %1, %2, %0"
      : "+a"(acc) : "a"(a), "v"(b));
}
__device__ __forceinline__ void mfma_fence(f32x4& acc0, f32x4& acc1) {
  asm volatile("s_nop 7\n\ts_nop 7\n\ts_nop 7" : "+a"(acc0), "+a"(acc1));
}

// One block (512 threads = 8 waves) per matrix (R13 structure, proven best:
// 123 us). Wave w owns rows [32w,32w+32) and cols [32w,32w+32) of V0 (bf16
// A-frags pinned in AGPRs). Scales broadcast through the MFMA B operand (all
// 16 n-cols identical -> D reg r = sum for row/col 4q+r, any lane). Floors:
// LDS 128 ds_read_b128/CU/iter ~1536 cyc; MFMA 64/SIMD/iter ~310 cyc.
// Layouts (m89-verified): A elem j <-> A[m=lane&15][k=8q+j]; D reg r <-> row
// 4q+r, col=lane&15.
__global__ __launch_bounds__(512)
__attribute__((amdgpu_waves_per_eu(2, 2)))
void sinkhorn_mfma8f(const float* __restrict__ alpha, float* __restrict__ out) {
  __shared__ alignas(16) unsigned short Cb16[256];
  __shared__ alignas(16) unsigned short Rb16[256];
  __shared__ alignas(16) float Cb32[256];
  __shared__ alignas(16) float Rb32[256];

  const int tid  = threadIdx.x;
  const int lane = tid & 63;
  const int w    = tid >> 6;   // wave 0..7
  const int m    = lane & 15;
  const int q    = lane >> 4;

  const size_t mbase = (size_t)blockIdx.x * (256 * 256);
  const float* A = alpha + mbase;
  float*       O = out + mbase;

  // arow[s][c] elem j <-> V0[32w+16s+m][32c+8q+j]
  // acol[s][c] elem j <-> V0[32c+8q+j][32w+16s+m]
  u32x4 arow[2][8];
  u32x4 acol[2][8];

#pragma unroll
  for (int s = 0; s < 2; ++s) {
    const float* rowp = A + (size_t)(32 * w + 16 * s + m) * 256 + 8 * q;
#pragma unroll
    for (int c = 0; c < 8; ++c) {
      float4 x0 = *(const float4*)(rowp + 32 * c);
      float4 x1 = *(const float4*)(rowp + 32 * c + 4);
      arow[s][c] = (u32x4){bf16pack(__expf(x0.x * 10.0f), __expf(x0.y * 10.0f)),
                           bf16pack(__expf(x0.z * 10.0f), __expf(x0.w * 10.0f)),
                           bf16pack(__expf(x1.x * 10.0f), __expf(x1.y * 10.0f)),
                           bf16pack(__expf(x1.z * 10.0f), __expf(x1.w * 10.0f))};
    }
    const float* colp = A + (size_t)(8 * q) * 256 + 32 * w + 16 * s + m;
#pragma unroll
    for (int c = 0; c < 8; ++c) {
      const float* p = colp + (size_t)(32 * c) * 256;
      acol[s][c] =
          (u32x4){bf16pack(__expf(p[0] * 10.0f), __expf(p[256] * 10.0f)),
                  bf16pack(__expf(p[512] * 10.0f), __expf(p[768] * 10.0f)),
                  bf16pack(__expf(p[1024] * 10.0f), __expf(p[1280] * 10.0f)),
                  bf16pack(__expf(p[1536] * 10.0f), __expf(p[1792] * 10.0f))};
    }
  }
  // Pin all persistent fragments into AGPRs (one-time, far from MFMAs).
#pragma unroll
  for (int s = 0; s < 2; ++s)
#pragma unroll
    for (int c = 0; c < 8; ++c) {
      pin_agpr(arow[s][c]);
      pin_agpr(acol[s][c]);
    }

  if (tid < 256) Cb16[tid] = 0x3F80;  // C = 1
  __syncthreads();

  for (int it = 0; it < N_ITER; ++it) {
    const bool last = (it == N_ITER - 1);

    // ---------- phase 1: s = V0_rowslabs · C ; R = 1/s ----------
    {
      u32x4 B[8];
#pragma unroll
      for (int c = 0; c < 8; ++c) B[c] = *(const u32x4*)&Cb16[32 * c + 8 * q];
      f32x4 acc0, acc1;
      mfma_first(acc0, arow[0][0], B[0]);
      mfma_first(acc1, arow[1][0], B[0]);
#pragma unroll
      for (int c = 1; c < 8; ++c) {
        mfma_aa(acc0, arow[0][c], B[c]);
        mfma_aa(acc1, arow[1][c], B[c]);
      }
      mfma_fence(acc0, acc1);
      if (m == 0) {  // rows 32w(+16)+4q..+3
        float r0 = __builtin_amdgcn_rcpf(acc0[0]);
        float r1 = __builtin_amdgcn_rcpf(acc0[1]);
        float r2 = __builtin_amdgcn_rcpf(acc0[2]);
        float r3 = __builtin_amdgcn_rcpf(acc0[3]);
        float r4 = __builtin_amdgcn_rcpf(acc1[0]);
        float r5 = __builtin_amdgcn_rcpf(acc1[1]);
        float r6 = __builtin_amdgcn_rcpf(acc1[2]);
        float r7 = __builtin_amdgcn_rcpf(acc1[3]);
        *(uint2*)&Rb16[32 * w + 4 * q] = make_uint2(bf16pack(r0, r1), bf16pack(r2, r3));
        *(uint2*)&Rb16[32 * w + 16 + 4 * q] = make_uint2(bf16pack(r4, r5), bf16pack(r6, r7));
        if (last) {
          *(float4*)&Rb32[32 * w + 4 * q] = make_float4(r0, r1, r2, r3);
          *(float4*)&Rb32[32 * w + 16 + 4 * q] = make_float4(r4, r5, r6, r7);
        }
      }
    }
    __syncthreads();

    // ---------- phase 2: t = V0^T_colslabs · R ; C = 1/t ----------
    {
      u32x4 B[8];
#pragma unroll
      for (int c = 0; c < 8; ++c) B[c] = *(const u32x4*)&Rb16[32 * c + 8 * q];
      f32x4 acc0, acc1;
      mfma_first(acc0, acol[0][0], B[0]);
      mfma_first(acc1, acol[1][0], B[0]);
#pragma unroll
      for (int c = 1; c < 8; ++c) {
        mfma_aa(acc0, acol[0][c], B[c]);
        mfma_aa(acc1, acol[1][c], B[c]);
      }
      mfma_fence(acc0, acc1);
      if (m == 0) {  // cols 32w(+16)+4q..+3
        float c0 = __builtin_amdgcn_rcpf(acc0[0]);
        float c1 = __builtin_amdgcn_rcpf(acc0[1]);
        float c2 = __builtin_amdgcn_rcpf(acc0[2]);
        float c3 = __builtin_amdgcn_rcpf(acc0[3]);
        float c4 = __builtin_amdgcn_rcpf(acc1[0]);
        float c5 = __builtin_amdgcn_rcpf(acc1[1]);
        float c6 = __builtin_amdgcn_rcpf(acc1[2]);
        float c7 = __builtin_amdgcn_rcpf(acc1[3]);
        *(uint2*)&Cb16[32 * w + 4 * q] = make_uint2(bf16pack(c0, c1), bf16pack(c2, c3));
        *(uint2*)&Cb16[32 * w + 16 + 4 * q] = make_uint2(bf16pack(c4, c5), bf16pack(c6, c7));
        if (last) {
          *(float4*)&Cb32[32 * w + 4 * q] = make_float4(c0, c1, c2, c3);
          *(float4*)&Cb32[32 * w + 16 + 4 * q] = make_float4(c4, c5, c6, c7);
        }
      }
    }
    __syncthreads();
  }

  // ---------- epilogue: out = diag(R32) · V0_bf16 · diag(C32) ----------
#pragma unroll
  for (int s = 0; s < 2; ++s) {
    const float Rm = Rb32[32 * w + 16 * s + m];
    float* dst = O + (size_t)(32 * w + 16 * s + m) * 256 + 8 * q;
#pragma unroll
    for (int c = 0; c < 8; ++c) {
      float4 c0 = *(const float4*)&Cb32[32 * c + 8 * q];
      float4 c1 = *(const float4*)&Cb32[32 * c + 8 * q + 4];
      u32x4 pk = arow[s][c];
      float4 o0, o1;
      o0.x = bflo(pk.x) * Rm * c0.x;
      o0.y = bfhi(pk.x) * Rm * c0.y;
      o0.z = bflo(pk.y) * Rm * c0.z;
      o0.w = bfhi(pk.y) * Rm * c0.w;
      o1.x = bflo(pk.z) * Rm * c1.x;
      o1.y = bfhi(pk.z) * Rm * c1.y;
      o1.z = bflo(pk.w) * Rm * c1.z;
      o1.w = bfhi(pk.w) * Rm * c1.w;
      *(float4*)(dst + 32 * c) = o0;
      *(float4*)(dst + 32 * c + 4) = o1;
    }
  }
}

extern "C" void kernel_launch(void* const* d_in, const int* in_sizes, int n_in,
                              void* d_out, int out_size, void* d_ws, size_t ws_size,
                              hipStream_t stream) {
  const float* alpha = (const float*)d_in[0];
  float* out = (float*)d_out;
  sinkhorn_mfma8f<<<dim3(16), dim3(512), 0, stream>>>(alpha, out);
}